// Round 10
// baseline (4320.132 us; speedup 1.0000x reference)
//
#include <hip/hip_runtime.h>

static inline int ceil_div(int a, int b) { return (a + b - 1) / b; }

typedef __attribute__((ext_vector_type(8))) short short8;
typedef __attribute__((ext_vector_type(4))) float floatx4;

__device__ __forceinline__ unsigned short f2bf(float f) {
    unsigned int u = __float_as_uint(f);
    unsigned int r = (u + 0x7fffu + ((u >> 16) & 1u)) >> 16;
    return (unsigned short)r;
}
__device__ __forceinline__ float bf2f(unsigned short h) {
    return __uint_as_float(((unsigned int)h) << 16);
}

// ---------------- CSR build ----------------
__global__ __launch_bounds__(256) void count_deg_k(const int* __restrict__ edges,
                                                   int* __restrict__ deg, int E) {
    int e = blockIdx.x * blockDim.x + threadIdx.x;
    if (e < E) {
        atomicAdd(&deg[edges[2 * e]], 1);
        atomicAdd(&deg[edges[2 * e + 1]], 1);
    }
}

__global__ __launch_bounds__(1024) void scan1_k(const int* __restrict__ deg,
                                                int* __restrict__ excl,
                                                int* __restrict__ bsum, int Nv) {
    __shared__ int s[1024];
    int tid = threadIdx.x;
    int i = blockIdx.x * 1024 + tid;
    int v = (i < Nv) ? deg[i] : 0;
    s[tid] = v;
    __syncthreads();
    for (int off = 1; off < 1024; off <<= 1) {
        int t = (tid >= off) ? s[tid - off] : 0;
        __syncthreads();
        if (tid >= off) s[tid] += t;
        __syncthreads();
    }
    if (i < Nv) excl[i] = s[tid] - v;
    if (tid == 1023) bsum[blockIdx.x] = s[1023];
}

__global__ __launch_bounds__(64) void scan2_k(int* __restrict__ bsum, int nb) {
    __shared__ int s[64];
    int tid = threadIdx.x;
    int v = (tid < nb) ? bsum[tid] : 0;
    s[tid] = v;
    __syncthreads();
    for (int off = 1; off < 64; off <<= 1) {
        int t = (tid >= off) ? s[tid - off] : 0;
        __syncthreads();
        if (tid >= off) s[tid] += t;
        __syncthreads();
    }
    if (tid < nb) bsum[tid] = s[tid] - v;
}

__global__ __launch_bounds__(1024) void scan3_k(const int* __restrict__ excl,
                                                const int* __restrict__ bsum,
                                                const int* __restrict__ deg,
                                                int* __restrict__ rowptr,
                                                int* __restrict__ cursor, int Nv) {
    int i = blockIdx.x * 1024 + threadIdx.x;
    if (i < Nv) {
        int val = excl[i] + bsum[blockIdx.x];
        rowptr[i] = val;
        cursor[i] = val;
        if (i == Nv - 1) rowptr[Nv] = val + deg[i];
    }
}

__global__ __launch_bounds__(256) void fill_adj_k(const int* __restrict__ edges,
                                                  int* __restrict__ cursor,
                                                  int* __restrict__ adj, int E) {
    int e = blockIdx.x * blockDim.x + threadIdx.x;
    if (e < E) {
        int a = edges[2 * e], b = edges[2 * e + 1];
        adj[atomicAdd(&cursor[a], 1)] = b;
        adj[atomicAdd(&cursor[b], 1)] = a;
    }
}

// ---------------- weight prep: fp32 [K][128] -> bf16 transposed [128 n][128 k] ----------------
__global__ __launch_bounds__(256) void prep_w_k(const float* __restrict__ g0w0,
                                                const float* __restrict__ g0w1,
                                                const float* __restrict__ gw0,
                                                const float* __restrict__ gw1,
                                                unsigned short* __restrict__ Wt) {
    int lh = blockIdx.x;
    int l = lh >> 1, h = lh & 1;
    const float* src;
    if (l == 0) src = h ? g0w1 : g0w0;
    else src = (h ? gw1 : gw0) + (size_t)(l - 1) * 16384;
    unsigned short* dst = Wt + (size_t)lh * 16384;
    for (int idx = threadIdx.x; idx < 16384; idx += 256) {
        int n = idx >> 7, k = idx & 127;
        dst[n * 128 + k] = f2bf(src[k * 128 + n]);
    }
}

// ---------------- enc @ g0_w*[131:387] ----------------
__global__ __launch_bounds__(128) void enc_proj_k(const float* __restrict__ enc,
                                                  const float* __restrict__ w0,
                                                  const float* __restrict__ w1,
                                                  float* __restrict__ out, int B_) {
    int b = blockIdx.x, sH = blockIdx.y, j = threadIdx.x;
    const float* w = sH ? w1 : w0;
    const float* eb = enc + b * 256;
    float acc = 0.f;
    for (int c = 0; c < 256; ++c) acc = fmaf(eb[c], w[(131 + c) * 128 + j], acc);
    out[(sH * B_ + b) * 128 + j] = acc;
}

// ---------------- fused pixel projection (all 4 levels, one launch) ----------------
// K-split Cchunk=64 into disjoint partial buffers q1..q4.
__global__ __launch_bounds__(256) void proj_all_k(
    const float* __restrict__ fm1, const float* __restrict__ fm2,
    const float* __restrict__ fm3, const float* __restrict__ fm4,
    const float* __restrict__ bw, float* __restrict__ q1, float* __restrict__ q2,
    float* __restrict__ q3, float* __restrict__ q4, int B_) {
    __shared__ float Xs[32][64];
    __shared__ float Ws[32][128];
    int tid = threadIdx.x;

    int n1 = 49 * B_ * 4, n2 = 13 * B_ * 8, n3 = 4 * B_ * 16;
    int bid = blockIdx.x;
    const float* fm;
    const float* W;
    float* op;
    int C, HW, PT, idx;
    if (bid < n1) {
        fm = fm1; W = bw; op = q1; C = 256; HW = 3136; PT = 49; idx = bid;
    } else if (bid < n1 + n2) {
        fm = fm2; W = bw + 256 * 128; op = q2; C = 512; HW = 784; PT = 13; idx = bid - n1;
    } else if (bid < n1 + n2 + n3) {
        fm = fm3; W = bw + 768 * 128; op = q3; C = 1024; HW = 196; PT = 4; idx = bid - n1 - n2;
    } else {
        fm = fm4; W = bw + 1792 * 128; op = q4; C = 2048; HW = 49; PT = 1;
        idx = bid - n1 - n2 - n3;
    }
    int pt = idx % PT;
    int r2 = idx / PT;
    int b = r2 % B_;
    int zz = r2 / B_;
    int p0 = pt * 64;
    int c0 = zz * 64;
    int S = B_ * HW * 128;
    const float* fmb = fm + (size_t)b * C * HW;

    float acc[8][4];
#pragma unroll
    for (int i = 0; i < 8; i++)
#pragma unroll
        for (int j = 0; j < 4; j++) acc[i][j] = 0.f;

    bool vec_ok = ((HW & 3) == 0);
    for (int kc = c0; kc < c0 + 64; kc += 32) {
        {
            int p4 = (tid & 15) * 4;
            int k0 = tid >> 4;
#pragma unroll
            for (int kk = 0; kk < 32; kk += 16) {
                int k = k0 + kk;
                const float* src = fmb + (size_t)(kc + k) * HW + p0 + p4;
                float4 v;
                if (vec_ok && (p0 + p4 + 3 < HW)) {
                    v = *(const float4*)src;
                } else {
                    v.x = (p0 + p4 + 0 < HW) ? src[0] : 0.f;
                    v.y = (p0 + p4 + 1 < HW) ? src[1] : 0.f;
                    v.z = (p0 + p4 + 2 < HW) ? src[2] : 0.f;
                    v.w = (p0 + p4 + 3 < HW) ? src[3] : 0.f;
                }
                *(float4*)&Xs[k][p4] = v;
            }
        }
        {
            int j4 = (tid & 31) * 4;
            int k0 = tid >> 5;
#pragma unroll
            for (int kk = 0; kk < 32; kk += 8) {
                int k = k0 + kk;
                *(float4*)&Ws[k][j4] = *(const float4*)(W + (size_t)(kc + k) * 128 + j4);
            }
        }
        __syncthreads();
        int rb = (tid >> 5) * 8;
        int cb = (tid & 31) * 4;
#pragma unroll 8
        for (int k = 0; k < 32; ++k) {
            float xr[8], wc[4];
#pragma unroll
            for (int i = 0; i < 8; i++) xr[i] = Xs[k][rb + i];
#pragma unroll
            for (int j = 0; j < 4; j++) wc[j] = Ws[k][cb + j];
#pragma unroll
            for (int i = 0; i < 8; i++)
#pragma unroll
                for (int j = 0; j < 4; j++) acc[i][j] = fmaf(xr[i], wc[j], acc[i][j]);
        }
        __syncthreads();
    }
    int rb = (tid >> 5) * 8;
    int cb = (tid & 31) * 4;
    float* obase = op + (size_t)zz * S;
#pragma unroll
    for (int i = 0; i < 8; i++) {
        int p = p0 + rb + i;
        if (p < HW) {
            *(float4*)(obase + ((size_t)b * HW + p) * 128 + cb) =
                make_float4(acc[i][0], acc[i][1], acc[i][2], acc[i][3]);
        }
    }
}

// ---------------- reduce partials for all 4 levels ----------------
__global__ __launch_bounds__(256) void reduce4_k(const float* __restrict__ q1,
                                                 const float* __restrict__ q2,
                                                 const float* __restrict__ q3,
                                                 const float* __restrict__ q4,
                                                 float* __restrict__ o1, float* __restrict__ o2,
                                                 float* __restrict__ o3, float* __restrict__ o4,
                                                 int S1, int S2, int S3, int S4) {
    int i = (blockIdx.x * 256 + threadIdx.x) * 4;
    const float* src;
    float* dst;
    int S, z, base;
    if (i < S1) {
        src = q1; dst = o1; S = S1; z = 4; base = i;
    } else if (i < S1 + S2) {
        src = q2; dst = o2; S = S2; z = 8; base = i - S1;
    } else if (i < S1 + S2 + S3) {
        src = q3; dst = o3; S = S3; z = 16; base = i - S1 - S2;
    } else if (i < S1 + S2 + S3 + S4) {
        src = q4; dst = o4; S = S4; z = 32; base = i - S1 - S2 - S3;
    } else {
        return;
    }
    float4 a = *(const float4*)(src + base);
    for (int zz = 1; zz < z; ++zz) {
        float4 b = *(const float4*)(src + (size_t)zz * S + base);
        a.x += b.x; a.y += b.y; a.z += b.z; a.w += b.w;
    }
    *(float4*)(dst + base) = a;
}

// ---------------- bilinear sample + bottleneck relu + layer0 pre terms ----------------
__device__ __forceinline__ float sample_level(const float* __restrict__ pp, int Hh, int Ww,
                                              float gx, float gy, int j) {
    float x = (gx + 1.f) * 0.5f * (float)(Ww - 1);
    float y = (gy + 1.f) * 0.5f * (float)(Hh - 1);
    float x0f = floorf(x), y0f = floorf(y);
    float wx1 = x - x0f, wy1 = y - y0f;
    float wx0 = 1.f - wx1, wy0 = 1.f - wy1;
    int x0 = (int)fminf(fmaxf(x0f, 0.f), (float)(Ww - 1));
    int x1 = (int)fminf(fmaxf(x0f + 1.f, 0.f), (float)(Ww - 1));
    int y0 = (int)fminf(fmaxf(y0f, 0.f), (float)(Hh - 1));
    int y1 = (int)fminf(fmaxf(y0f + 1.f, 0.f), (float)(Hh - 1));
    const float* r00 = pp + (size_t)(y0 * Ww + x0) * 128;
    const float* r01 = pp + (size_t)(y0 * Ww + x1) * 128;
    const float* r10 = pp + (size_t)(y1 * Ww + x0) * 128;
    const float* r11 = pp + (size_t)(y1 * Ww + x1) * 128;
    return wy0 * (wx0 * r00[j] + wx1 * r01[j]) + wy1 * (wx0 * r10[j] + wx1 * r11[j]);
}

__global__ __launch_bounds__(128) void sample_bottleneck_k(
    const float* __restrict__ av, const float* __restrict__ pp1, const float* __restrict__ pp2,
    const float* __restrict__ pp3, const float* __restrict__ pp4, const float* __restrict__ bb,
    const float* __restrict__ verts, const float* __restrict__ encp,
    const float* __restrict__ g0w0, const float* __restrict__ g0w1,
    const float* __restrict__ g0b0, const float* __restrict__ g0b1,
    unsigned short* __restrict__ X, unsigned short* __restrict__ H, int V_, int B_) {
    int n = blockIdx.x, j = threadIdx.x;
    int b = n / V_;
    float gx = av[(size_t)n * 3 + 0];
    float gy = av[(size_t)n * 3 + 1];
    float acc = bb[j];
    acc += sample_level(pp1 + (size_t)b * 3136 * 128, 56, 56, gx, gy, j);
    acc += sample_level(pp2 + (size_t)b * 784 * 128, 28, 28, gx, gy, j);
    acc += sample_level(pp3 + (size_t)b * 196 * 128, 14, 14, gx, gy, j);
    acc += sample_level(pp4 + (size_t)b * 49 * 128, 7, 7, gx, gy, j);
    X[(size_t)n * 128 + j] = f2bf(fmaxf(acc, 0.f));
    float v0 = verts[n * 3 + 0], v1 = verts[n * 3 + 1], v2 = verts[n * 3 + 2];
    float h0 = encp[(0 * B_ + b) * 128 + j] + g0b0[j] + v0 * g0w0[128 * 128 + j] +
               v1 * g0w0[129 * 128 + j] + v2 * g0w0[130 * 128 + j];
    float h1 = encp[(1 * B_ + b) * 128 + j] + g0b1[j] + v0 * g0w1[128 * 128 + j] +
               v1 * g0w1[129 * 128 + j] + v2 * g0w1[130 * 128 + j];
    H[(size_t)n * 256 + j] = f2bf(h0);
    H[(size_t)n * 256 + 128 + j] = f2bf(h1);
}

// ---------------- layer-0 pre: pre[n] = h0pre[n] + sum_nb h1pre[nb] (fp32) ----------------
__global__ __launch_bounds__(256) void aggpre_k(const unsigned short* __restrict__ H,
                                                const int* __restrict__ rowptr,
                                                const int* __restrict__ adj,
                                                float* __restrict__ pre, int Nv) {
    int wave = threadIdx.x >> 6, lane = threadIdx.x & 63;
    int n = blockIdx.x * 4 + wave;
    if (n >= Nv) return;
    unsigned int u = *(const unsigned int*)(H + (size_t)n * 256 + 2 * lane);
    float a0 = bf2f((unsigned short)(u & 0xffff));
    float a1 = bf2f((unsigned short)(u >> 16));
    int s = rowptr[n], e = rowptr[n + 1];
    for (int t = s; t < e; ++t) {
        int nb = adj[t];
        unsigned int w = *(const unsigned int*)(H + (size_t)nb * 256 + 128 + 2 * lane);
        a0 += bf2f((unsigned short)(w & 0xffff));
        a1 += bf2f((unsigned short)(w >> 16));
    }
    pre[(size_t)n * 128 + 2 * lane] = a0;
    pre[(size_t)n * 128 + 2 * lane + 1] = a1;
}

// ---------------- persistent 8-layer GraphConv + head ----------------
// grid = ceil(N/64) blocks (641), guaranteed >=3 blocks/CU co-resident
// (32KB LDS, launch_bounds(256,3)). Device-scope atomic grid barrier.
__device__ __forceinline__ void gbar(unsigned int* ctr, unsigned int nb) {
    __syncthreads();
    if (threadIdx.x == 0) {
        __threadfence();
        __hip_atomic_fetch_add(ctr, 1u, __ATOMIC_ACQ_REL, __HIP_MEMORY_SCOPE_AGENT);
        while (__hip_atomic_load(ctr, __ATOMIC_ACQUIRE, __HIP_MEMORY_SCOPE_AGENT) < nb) {
            __builtin_amdgcn_s_sleep(2);
        }
    }
    __syncthreads();
    __threadfence();
}

__global__ __launch_bounds__(256, 3) void layers_persist_k(
    unsigned short* __restrict__ XA, unsigned short* __restrict__ XB,
    unsigned short* __restrict__ Agg, const unsigned short* __restrict__ Wt,
    const float* __restrict__ gb0, const float* __restrict__ gb1,
    const float* __restrict__ pre, const int* __restrict__ degv,
    const int* __restrict__ rowptr, const int* __restrict__ adj,
    const float* __restrict__ off_w, const float* __restrict__ off_b,
    float* __restrict__ out, unsigned int* __restrict__ bars, int M) {
    __shared__ unsigned short lds[16384];  // 32 KB weight stage / Cs reuse

    int tid = threadIdx.x;
    int wave = tid >> 6, lane = tid & 63;
    int row16 = lane & 15;
    int quad = lane >> 4;
    int wrow = wave * 16;
    unsigned int NB = gridDim.x;
    int m0 = blockIdx.x * 64;

    const unsigned short* cur = XA;
    unsigned short* nxt = XB;

    for (int l = 0; l < 8; ++l) {
        // ---- phase A: Agg[n] = sum_nb cur[nb] ----
        const unsigned int* Xu = (const unsigned int*)cur;
        for (int n = blockIdx.x * 4 + wave; n < M; n += NB * 4) {
            float a0 = 0.f, a1 = 0.f;
            int s = rowptr[n], e = rowptr[n + 1];
            for (int t = s; t < e; ++t) {
                int nb2 = adj[t];
                unsigned int w = Xu[(size_t)nb2 * 64 + lane];
                a0 += bf2f((unsigned short)(w & 0xffff));
                a1 += bf2f((unsigned short)(w >> 16));
            }
            unsigned int o = (unsigned int)f2bf(a0) | ((unsigned int)f2bf(a1) << 16);
            *(unsigned int*)(Agg + (size_t)n * 128 + 2 * lane) = o;
        }
        gbar(&bars[2 * l], NB);

        // ---- phase B: nxt = relu(cur@W0 + Agg@W1 + b0 + deg*b1 (+pre)) ----
        const unsigned short* Wl = Wt + (size_t)l * 32768;
        const float* b0 = (l == 0) ? nullptr : gb0 + (l - 1) * 128;
        const float* b1 = (l == 0) ? nullptr : gb1 + (l - 1) * 128;
        const float* prel = (l == 0) ? pre : nullptr;

        for (int yb = 0; yb < 2; ++yb) {
            __syncthreads();  // protect lds vs previous iteration readers
            const unsigned short* W0h = Wl + (size_t)yb * 64 * 128;
            const unsigned short* W1h = Wl + 16384 + (size_t)yb * 64 * 128;
#pragma unroll
            for (int ll = 0; ll < 8; ++ll) {
                int idx = tid + ll * 256;
                int half = idx >> 10;
                int r = (idx >> 4) & 63;
                int c16 = idx & 15;
                int sw = (c16 ^ (r & 15)) * 8;
                const unsigned short* src = (half ? W1h : W0h) + r * 128 + c16 * 8;
                *(short8*)&lds[half * 8192 + r * 128 + sw] = *(const short8*)src;
            }
            __syncthreads();

            floatx4 acc[4];
#pragma unroll
            for (int j = 0; j < 4; j++) acc[j] = (floatx4){0.f, 0.f, 0.f, 0.f};

#pragma unroll
            for (int ks = 0; ks < 4; ++ks) {
                int koff = ks * 32 + quad * 8;
                int g = min(m0 + wrow + row16, M - 1);
                short8 ax = *(const short8*)(cur + (size_t)g * 128 + koff);
                short8 ag = *(const short8*)(Agg + (size_t)g * 128 + koff);
                int c = ks * 4 + quad;
#pragma unroll
                for (int nt = 0; nt < 4; ++nt) {
                    int wr = nt * 16 + row16;
                    short8 bw0 = *(short8*)&lds[wr * 128 + ((c ^ row16) * 8)];
                    short8 bw1 = *(short8*)&lds[8192 + wr * 128 + ((c ^ row16) * 8)];
                    acc[nt] = __builtin_amdgcn_mfma_f32_16x16x32_bf16(ax, bw0, acc[nt], 0, 0, 0);
                    acc[nt] = __builtin_amdgcn_mfma_f32_16x16x32_bf16(ag, bw1, acc[nt], 0, 0, 0);
                }
            }
            __syncthreads();  // weights consumed; reuse lds as Cs (64 x pitch-72)

            unsigned short* Cs = lds;
#pragma unroll
            for (int nt = 0; nt < 4; ++nt) {
                int colh = nt * 16 + row16;
                int colg = yb * 64 + colh;
                float bc0 = b0 ? b0[colg] : 0.f;
                float bc1 = b1 ? b1[colg] : 0.f;
#pragma unroll
                for (int rr = 0; rr < 4; ++rr) {
                    int row = wrow + quad * 4 + rr;
                    int gm = m0 + row;
                    float v = acc[nt][rr] + bc0;
                    if (gm < M) {
                        v += (float)degv[gm] * bc1;
                        if (prel) v += prel[(size_t)gm * 128 + colg];
                    }
                    Cs[row * 72 + colh] = f2bf(fmaxf(v, 0.f));
                }
            }
            __syncthreads();

            int r = tid >> 2;
            int cq = (tid & 3) * 16;
            int gm = m0 + r;
            if (gm < M) {
                unsigned short* dst = nxt + (size_t)gm * 128 + yb * 64 + cq;
                *(short8*)dst = *(short8*)&Cs[r * 72 + cq];
                *(short8*)(dst + 8) = *(short8*)&Cs[r * 72 + cq + 8];
            }
        }
        gbar(&bars[2 * l + 1], NB);

        const unsigned short* t = cur;
        cur = nxt;
        nxt = (unsigned short*)t;
    }

    // ---- head: out = cur @ off_w + off_b ----
    for (int n = blockIdx.x * 4 + wave; n < M; n += NB * 4) {
        unsigned int u = *(const unsigned int*)(cur + (size_t)n * 128 + 2 * lane);
        float x0 = bf2f((unsigned short)(u & 0xffff));
        float x1 = bf2f((unsigned short)(u >> 16));
        int c0 = 2 * lane, c1 = 2 * lane + 1;
        float p0 = x0 * off_w[c0 * 3 + 0] + x1 * off_w[c1 * 3 + 0];
        float p1 = x0 * off_w[c0 * 3 + 1] + x1 * off_w[c1 * 3 + 1];
        float p2 = x0 * off_w[c0 * 3 + 2] + x1 * off_w[c1 * 3 + 2];
#pragma unroll
        for (int m = 1; m < 64; m <<= 1) {
            p0 += __shfl_xor(p0, m);
            p1 += __shfl_xor(p1, m);
            p2 += __shfl_xor(p2, m);
        }
        if (lane == 0) {
            out[n * 3 + 0] = p0 + off_b[0];
            out[n * 3 + 1] = p1 + off_b[1];
            out[n * 3 + 2] = p2 + off_b[2];
        }
    }
}

extern "C" void kernel_launch(void* const* d_in, const int* in_sizes, int n_in, void* d_out,
                              int out_size, void* d_ws, size_t ws_size, hipStream_t stream) {
    const float* feat1 = (const float*)d_in[0];
    const float* feat2 = (const float*)d_in[1];
    const float* feat3 = (const float*)d_in[2];
    const float* feat4 = (const float*)d_in[3];
    const float* av = (const float*)d_in[4];
    const float* verts = (const float*)d_in[5];
    const float* image_enc = (const float*)d_in[6];
    const int* edges = (const int*)d_in[7];
    const float* bw = (const float*)d_in[8];
    const float* bb = (const float*)d_in[9];
    const float* g0w0 = (const float*)d_in[10];
    const float* g0b0 = (const float*)d_in[11];
    const float* g0w1 = (const float*)d_in[12];
    const float* g0b1 = (const float*)d_in[13];
    const float* gw0 = (const float*)d_in[14];
    const float* gb0 = (const float*)d_in[15];
    const float* gw1 = (const float*)d_in[16];
    const float* gb1 = (const float*)d_in[17];
    const float* off_w = (const float*)d_in[18];
    const float* off_b = (const float*)d_in[19];

    int B_ = in_sizes[6] / 256;  // 4
    int N_ = in_sizes[5] / 3;    // 40968
    int V_ = N_ / B_;            // 10242
    int E_ = in_sizes[7] / 2;    // 122880

    char* wsb = (char*)d_ws;
    size_t off = 0;
    auto alloc = [&](size_t bytes) -> void* {
        void* p = (void*)(wsb + off);
        off += (bytes + 255) & ~(size_t)255;
        return p;
    };
    int S1 = B_ * 3136 * 128;
    int S2 = B_ * 784 * 128;
    int S3 = B_ * 196 * 128;
    int S4 = B_ * 49 * 128;
    float* pp1 = (float*)alloc((size_t)S1 * 4);
    float* pp2 = (float*)alloc((size_t)S2 * 4);
    float* pp3 = (float*)alloc((size_t)S3 * 4);
    float* pp4 = (float*)alloc((size_t)S4 * 4);
    float* q1 = (float*)alloc((size_t)4 * S1 * 4);
    float* q2 = (float*)alloc((size_t)8 * S2 * 4);
    float* q3 = (float*)alloc((size_t)16 * S3 * 4);
    float* q4 = (float*)alloc((size_t)32 * S4 * 4);
    unsigned short* XA = (unsigned short*)alloc((size_t)N_ * 128 * 2);
    unsigned short* XB = (unsigned short*)alloc((size_t)N_ * 128 * 2);
    unsigned short* AggB = (unsigned short*)alloc((size_t)N_ * 128 * 2);
    unsigned short* Hb = (unsigned short*)alloc((size_t)N_ * 256 * 2);
    float* pre = (float*)alloc((size_t)N_ * 128 * 4);
    unsigned short* Wt = (unsigned short*)alloc((size_t)8 * 2 * 128 * 128 * 2);
    float* encp = (float*)alloc((size_t)2 * B_ * 128 * 4);
    int* deg = (int*)alloc((size_t)(N_ + 1) * 4);
    int* rowptr = (int*)alloc((size_t)(N_ + 1) * 4);
    int* cursor = (int*)alloc((size_t)N_ * 4);
    int* excl = (int*)alloc((size_t)N_ * 4);
    int* bsum = (int*)alloc((size_t)64 * 4);
    int* adj = (int*)alloc((size_t)2 * E_ * 4);
    unsigned int* bars = (unsigned int*)alloc((size_t)32 * 4);

    // zero CSR counters + barrier counters
    hipMemsetAsync(deg, 0, (N_ + 1) * sizeof(int), stream);
    hipMemsetAsync(bars, 0, 32 * sizeof(unsigned int), stream);

    // CSR build
    count_deg_k<<<ceil_div(E_, 256), 256, 0, stream>>>(edges, deg, E_);
    int nb = ceil_div(N_, 1024);
    scan1_k<<<nb, 1024, 0, stream>>>(deg, excl, bsum, N_);
    scan2_k<<<1, 64, 0, stream>>>(bsum, nb);
    scan3_k<<<nb, 1024, 0, stream>>>(excl, bsum, deg, rowptr, cursor, N_);
    fill_adj_k<<<ceil_div(E_, 256), 256, 0, stream>>>(edges, cursor, adj, E_);

    // weight prep + enc projection
    prep_w_k<<<16, 256, 0, stream>>>(g0w0, g0w1, gw0, gw1, Wt);
    enc_proj_k<<<dim3(B_, 2), 128, 0, stream>>>(image_enc, g0w0, g0w1, encp, B_);

    // fused pixel projection (all levels, one launch) + 4-level reduce
    int nproj = 49 * B_ * 4 + 13 * B_ * 8 + 4 * B_ * 16 + 1 * B_ * 32;
    proj_all_k<<<nproj, 256, 0, stream>>>(feat1, feat2, feat3, feat4, bw, q1, q2, q3, q4, B_);
    int tot4 = (S1 + S2 + S3 + S4) / 4;
    reduce4_k<<<ceil_div(tot4, 256), 256, 0, stream>>>(q1, q2, q3, q4, pp1, pp2, pp3, pp4, S1,
                                                       S2, S3, S4);

    // sample + bottleneck -> XA (bf16 X0); layer0 pre terms (biases baked) -> Hb (bf16)
    sample_bottleneck_k<<<N_, 128, 0, stream>>>(av, pp1, pp2, pp3, pp4, bb, verts, encp, g0w0,
                                                g0w1, g0b0, g0b1, XA, Hb, V_, B_);

    // layer0 pre = h0pre + sum_nb h1pre
    aggpre_k<<<ceil_div(N_, 4), 256, 0, stream>>>(Hb, rowptr, adj, pre, N_);

    // persistent 8-layer chain + head (641 blocks, self-barriered)
    int lgrid = ceil_div(N_, 64);
    layers_persist_k<<<lgrid, 256, 0, stream>>>(XA, XB, AggB, Wt, gb0, gb1, pre, deg, rowptr,
                                                adj, off_w, off_b, (float*)d_out, bars, N_);
}

// Round 11
// 593.814 us; speedup vs baseline: 7.2752x; 7.2752x over previous
//
#include <hip/hip_runtime.h>

static inline int ceil_div(int a, int b) { return (a + b - 1) / b; }

typedef __attribute__((ext_vector_type(8))) short short8;
typedef __attribute__((ext_vector_type(4))) float floatx4;

__device__ __forceinline__ unsigned short f2bf(float f) {
    unsigned int u = __float_as_uint(f);
    unsigned int r = (u + 0x7fffu + ((u >> 16) & 1u)) >> 16;
    return (unsigned short)r;
}
__device__ __forceinline__ float bf2f(unsigned short h) {
    return __uint_as_float(((unsigned int)h) << 16);
}

// ---------------- CSR scan ----------------
__global__ __launch_bounds__(1024) void scan1_k(const int* __restrict__ deg,
                                                int* __restrict__ excl,
                                                int* __restrict__ bsum, int Nv) {
    __shared__ int s[1024];
    int tid = threadIdx.x;
    int i = blockIdx.x * 1024 + tid;
    int v = (i < Nv) ? deg[i] : 0;
    s[tid] = v;
    __syncthreads();
    for (int off = 1; off < 1024; off <<= 1) {
        int t = (tid >= off) ? s[tid - off] : 0;
        __syncthreads();
        if (tid >= off) s[tid] += t;
        __syncthreads();
    }
    if (i < Nv) excl[i] = s[tid] - v;
    if (tid == 1023) bsum[blockIdx.x] = s[1023];
}

__global__ __launch_bounds__(64) void scan2_k(int* __restrict__ bsum, int nb) {
    __shared__ int s[64];
    int tid = threadIdx.x;
    int v = (tid < nb) ? bsum[tid] : 0;
    s[tid] = v;
    __syncthreads();
    for (int off = 1; off < 64; off <<= 1) {
        int t = (tid >= off) ? s[tid - off] : 0;
        __syncthreads();
        if (tid >= off) s[tid] += t;
        __syncthreads();
    }
    if (tid < nb) bsum[tid] = s[tid] - v;
}

__global__ __launch_bounds__(1024) void scan3_k(const int* __restrict__ excl,
                                                const int* __restrict__ bsum,
                                                const int* __restrict__ deg,
                                                int* __restrict__ rowptr,
                                                int* __restrict__ cursor, int Nv) {
    int i = blockIdx.x * 1024 + threadIdx.x;
    if (i < Nv) {
        int val = excl[i] + bsum[blockIdx.x];
        rowptr[i] = val;
        cursor[i] = val;
        if (i == Nv - 1) rowptr[Nv] = val + deg[i];
    }
}

__global__ __launch_bounds__(256) void fill_adj_k(const int* __restrict__ edges,
                                                  int* __restrict__ cursor,
                                                  int* __restrict__ adj, int E) {
    int e = blockIdx.x * blockDim.x + threadIdx.x;
    if (e < E) {
        int a = edges[2 * e], b = edges[2 * e + 1];
        adj[atomicAdd(&cursor[a], 1)] = b;
        adj[atomicAdd(&cursor[b], 1)] = a;
    }
}

// ---------------- fat prologue: count_deg | prep_w | enc_proj (role by block range) ----------------
__global__ __launch_bounds__(256) void fatpre_k(const int* __restrict__ edges,
                                                int* __restrict__ deg, int E, int nE,
                                                const float* __restrict__ g0w0,
                                                const float* __restrict__ g0w1,
                                                const float* __restrict__ gw0,
                                                const float* __restrict__ gw1,
                                                unsigned short* __restrict__ Wt,
                                                const float* __restrict__ enc,
                                                float* __restrict__ encp, int B_) {
    int bid = blockIdx.x;
    int tid = threadIdx.x;
    if (bid < nE) {
        int e = bid * 256 + tid;
        if (e < E) {
            atomicAdd(&deg[edges[2 * e]], 1);
            atomicAdd(&deg[edges[2 * e + 1]], 1);
        }
    } else if (bid < nE + 16) {
        int lh = bid - nE;
        int l = lh >> 1, h = lh & 1;
        const float* src;
        if (l == 0) src = h ? g0w1 : g0w0;
        else src = (h ? gw1 : gw0) + (size_t)(l - 1) * 16384;
        unsigned short* dst = Wt + (size_t)lh * 16384;
        for (int idx = tid; idx < 16384; idx += 256) {
            int n = idx >> 7, k = idx & 127;
            dst[n * 128 + k] = f2bf(src[k * 128 + n]);
        }
    } else {
        int b = bid - nE - 16;  // 0..B_-1
        int sH = tid >> 7;
        int j = tid & 127;
        const float* w = sH ? g0w1 : g0w0;
        const float* eb = enc + b * 256;
        float acc = 0.f;
        for (int c = 0; c < 256; ++c) acc = fmaf(eb[c], w[(131 + c) * 128 + j], acc);
        encp[(sH * B_ + b) * 128 + j] = acc;
    }
}

// ---------------- fused pixel projection (all 4 levels, one launch) ----------------
__global__ __launch_bounds__(256) void proj_all_k(
    const float* __restrict__ fm1, const float* __restrict__ fm2,
    const float* __restrict__ fm3, const float* __restrict__ fm4,
    const float* __restrict__ bw, float* __restrict__ q1, float* __restrict__ q2,
    float* __restrict__ q3, float* __restrict__ q4, int B_) {
    __shared__ float Xs[32][64];
    __shared__ float Ws[32][128];
    int tid = threadIdx.x;

    int n1 = 49 * B_ * 4, n2 = 13 * B_ * 8, n3 = 4 * B_ * 16;
    int bid = blockIdx.x;
    const float* fm;
    const float* W;
    float* op;
    int C, HW, PT, idx;
    if (bid < n1) {
        fm = fm1; W = bw; op = q1; C = 256; HW = 3136; PT = 49; idx = bid;
    } else if (bid < n1 + n2) {
        fm = fm2; W = bw + 256 * 128; op = q2; C = 512; HW = 784; PT = 13; idx = bid - n1;
    } else if (bid < n1 + n2 + n3) {
        fm = fm3; W = bw + 768 * 128; op = q3; C = 1024; HW = 196; PT = 4; idx = bid - n1 - n2;
    } else {
        fm = fm4; W = bw + 1792 * 128; op = q4; C = 2048; HW = 49; PT = 1;
        idx = bid - n1 - n2 - n3;
    }
    int pt = idx % PT;
    int r2 = idx / PT;
    int b = r2 % B_;
    int zz = r2 / B_;
    int p0 = pt * 64;
    int c0 = zz * 64;
    int S = B_ * HW * 128;
    const float* fmb = fm + (size_t)b * C * HW;

    float acc[8][4];
#pragma unroll
    for (int i = 0; i < 8; i++)
#pragma unroll
        for (int j = 0; j < 4; j++) acc[i][j] = 0.f;

    bool vec_ok = ((HW & 3) == 0);
    for (int kc = c0; kc < c0 + 64; kc += 32) {
        {
            int p4 = (tid & 15) * 4;
            int k0 = tid >> 4;
#pragma unroll
            for (int kk = 0; kk < 32; kk += 16) {
                int k = k0 + kk;
                const float* src = fmb + (size_t)(kc + k) * HW + p0 + p4;
                float4 v;
                if (vec_ok && (p0 + p4 + 3 < HW)) {
                    v = *(const float4*)src;
                } else {
                    v.x = (p0 + p4 + 0 < HW) ? src[0] : 0.f;
                    v.y = (p0 + p4 + 1 < HW) ? src[1] : 0.f;
                    v.z = (p0 + p4 + 2 < HW) ? src[2] : 0.f;
                    v.w = (p0 + p4 + 3 < HW) ? src[3] : 0.f;
                }
                *(float4*)&Xs[k][p4] = v;
            }
        }
        {
            int j4 = (tid & 31) * 4;
            int k0 = tid >> 5;
#pragma unroll
            for (int kk = 0; kk < 32; kk += 8) {
                int k = k0 + kk;
                *(float4*)&Ws[k][j4] = *(const float4*)(W + (size_t)(kc + k) * 128 + j4);
            }
        }
        __syncthreads();
        int rb = (tid >> 5) * 8;
        int cb = (tid & 31) * 4;
#pragma unroll 8
        for (int k = 0; k < 32; ++k) {
            float xr[8], wc[4];
#pragma unroll
            for (int i = 0; i < 8; i++) xr[i] = Xs[k][rb + i];
#pragma unroll
            for (int j = 0; j < 4; j++) wc[j] = Ws[k][cb + j];
#pragma unroll
            for (int i = 0; i < 8; i++)
#pragma unroll
                for (int j = 0; j < 4; j++) acc[i][j] = fmaf(xr[i], wc[j], acc[i][j]);
        }
        __syncthreads();
    }
    int rb = (tid >> 5) * 8;
    int cb = (tid & 31) * 4;
    float* obase = op + (size_t)zz * S;
#pragma unroll
    for (int i = 0; i < 8; i++) {
        int p = p0 + rb + i;
        if (p < HW) {
            *(float4*)(obase + ((size_t)b * HW + p) * 128 + cb) =
                make_float4(acc[i][0], acc[i][1], acc[i][2], acc[i][3]);
        }
    }
}

// ---------------- reduce partials for all 4 levels ----------------
__global__ __launch_bounds__(256) void reduce4_k(const float* __restrict__ q1,
                                                 const float* __restrict__ q2,
                                                 const float* __restrict__ q3,
                                                 const float* __restrict__ q4,
                                                 float* __restrict__ o1, float* __restrict__ o2,
                                                 float* __restrict__ o3, float* __restrict__ o4,
                                                 int S1, int S2, int S3, int S4) {
    int i = (blockIdx.x * 256 + threadIdx.x) * 4;
    const float* src;
    float* dst;
    int S, z, base;
    if (i < S1) {
        src = q1; dst = o1; S = S1; z = 4; base = i;
    } else if (i < S1 + S2) {
        src = q2; dst = o2; S = S2; z = 8; base = i - S1;
    } else if (i < S1 + S2 + S3) {
        src = q3; dst = o3; S = S3; z = 16; base = i - S1 - S2;
    } else if (i < S1 + S2 + S3 + S4) {
        src = q4; dst = o4; S = S4; z = 32; base = i - S1 - S2 - S3;
    } else {
        return;
    }
    float4 a = *(const float4*)(src + base);
    for (int zz = 1; zz < z; ++zz) {
        float4 b = *(const float4*)(src + (size_t)zz * S + base);
        a.x += b.x; a.y += b.y; a.z += b.z; a.w += b.w;
    }
    *(float4*)(dst + base) = a;
}

// ---------------- bilinear sample + bottleneck relu + layer0 pre terms ----------------
__device__ __forceinline__ float sample_level(const float* __restrict__ pp, int Hh, int Ww,
                                              float gx, float gy, int j) {
    float x = (gx + 1.f) * 0.5f * (float)(Ww - 1);
    float y = (gy + 1.f) * 0.5f * (float)(Hh - 1);
    float x0f = floorf(x), y0f = floorf(y);
    float wx1 = x - x0f, wy1 = y - y0f;
    float wx0 = 1.f - wx1, wy0 = 1.f - wy1;
    int x0 = (int)fminf(fmaxf(x0f, 0.f), (float)(Ww - 1));
    int x1 = (int)fminf(fmaxf(x0f + 1.f, 0.f), (float)(Ww - 1));
    int y0 = (int)fminf(fmaxf(y0f, 0.f), (float)(Hh - 1));
    int y1 = (int)fminf(fmaxf(y0f + 1.f, 0.f), (float)(Hh - 1));
    const float* r00 = pp + (size_t)(y0 * Ww + x0) * 128;
    const float* r01 = pp + (size_t)(y0 * Ww + x1) * 128;
    const float* r10 = pp + (size_t)(y1 * Ww + x0) * 128;
    const float* r11 = pp + (size_t)(y1 * Ww + x1) * 128;
    return wy0 * (wx0 * r00[j] + wx1 * r01[j]) + wy1 * (wx0 * r10[j] + wx1 * r11[j]);
}

__global__ __launch_bounds__(128) void sample_bottleneck_k(
    const float* __restrict__ av, const float* __restrict__ pp1, const float* __restrict__ pp2,
    const float* __restrict__ pp3, const float* __restrict__ pp4, const float* __restrict__ bb,
    const float* __restrict__ verts, const float* __restrict__ encp,
    const float* __restrict__ g0w0, const float* __restrict__ g0w1,
    const float* __restrict__ g0b0, const float* __restrict__ g0b1,
    unsigned short* __restrict__ X, unsigned short* __restrict__ H, int V_, int B_) {
    int n = blockIdx.x, j = threadIdx.x;
    int b = n / V_;
    float gx = av[(size_t)n * 3 + 0];
    float gy = av[(size_t)n * 3 + 1];
    float acc = bb[j];
    acc += sample_level(pp1 + (size_t)b * 3136 * 128, 56, 56, gx, gy, j);
    acc += sample_level(pp2 + (size_t)b * 784 * 128, 28, 28, gx, gy, j);
    acc += sample_level(pp3 + (size_t)b * 196 * 128, 14, 14, gx, gy, j);
    acc += sample_level(pp4 + (size_t)b * 49 * 128, 7, 7, gx, gy, j);
    X[(size_t)n * 128 + j] = f2bf(fmaxf(acc, 0.f));
    float v0 = verts[n * 3 + 0], v1 = verts[n * 3 + 1], v2 = verts[n * 3 + 2];
    float h0 = encp[(0 * B_ + b) * 128 + j] + g0b0[j] + v0 * g0w0[128 * 128 + j] +
               v1 * g0w0[129 * 128 + j] + v2 * g0w0[130 * 128 + j];
    float h1 = encp[(1 * B_ + b) * 128 + j] + g0b1[j] + v0 * g0w1[128 * 128 + j] +
               v1 * g0w1[129 * 128 + j] + v2 * g0w1[130 * 128 + j];
    H[(size_t)n * 256 + j] = f2bf(h0);
    H[(size_t)n * 256 + 128 + j] = f2bf(h1);
}

// ---------------- layer-0 pre: pre[n] = h0pre[n] + sum_nb h1pre[nb] (fp32) ----------------
__global__ __launch_bounds__(256) void aggpre_k(const unsigned short* __restrict__ H,
                                                const int* __restrict__ rowptr,
                                                const int* __restrict__ adj,
                                                float* __restrict__ pre, int Nv) {
    int wave = threadIdx.x >> 6, lane = threadIdx.x & 63;
    int n = blockIdx.x * 4 + wave;
    if (n >= Nv) return;
    unsigned int u = *(const unsigned int*)(H + (size_t)n * 256 + 2 * lane);
    float a0 = bf2f((unsigned short)(u & 0xffff));
    float a1 = bf2f((unsigned short)(u >> 16));
    int s = rowptr[n], e = rowptr[n + 1];
    for (int t = s; t < e; ++t) {
        int nb = adj[t];
        unsigned int w = *(const unsigned int*)(H + (size_t)nb * 256 + 128 + 2 * lane);
        a0 += bf2f((unsigned short)(w & 0xffff));
        a1 += bf2f((unsigned short)(w >> 16));
    }
    pre[(size_t)n * 128 + 2 * lane] = a0;
    pre[(size_t)n * 128 + 2 * lane + 1] = a1;
}

// ---------------- neighbor aggregation: Agg[n] = sum_nb X[nb] (bf16, fp32 acc) ----------------
__global__ __launch_bounds__(256) void agg_x_k(const unsigned short* __restrict__ X,
                                               const int* __restrict__ rowptr,
                                               const int* __restrict__ adj,
                                               unsigned short* __restrict__ Agg, int Nv) {
    int wave = threadIdx.x >> 6, lane = threadIdx.x & 63;
    int n = blockIdx.x * 4 + wave;
    if (n >= Nv) return;
    const unsigned int* Xu = (const unsigned int*)X;
    float a0 = 0.f, a1 = 0.f;
    int s = rowptr[n], e = rowptr[n + 1];
    for (int t = s; t < e; ++t) {
        int nb = adj[t];
        unsigned int w = Xu[(size_t)nb * 64 + lane];
        a0 += bf2f((unsigned short)(w & 0xffff));
        a1 += bf2f((unsigned short)(w >> 16));
    }
    unsigned int o = (unsigned int)f2bf(a0) | ((unsigned int)f2bf(a1) << 16);
    *(unsigned int*)(Agg + (size_t)n * 128 + 2 * lane) = o;
}

// ---------------- dual-MFMA layer GEMM v2: A-prefetch before weight staging ----------------
// X' = relu(X@W0 + Agg@W1 + b0 + deg*b1 (+pre)). grid = (ceil(M/64), 2).
__global__ __launch_bounds__(256, 4) void gemm_dual_k(
    const unsigned short* __restrict__ Xin, const unsigned short* __restrict__ Agg,
    const unsigned short* __restrict__ Wt,  // [2][128][128] bf16 n-major (W0, W1)
    const float* __restrict__ b0, const float* __restrict__ b1,
    const float* __restrict__ pre, const int* __restrict__ degv,
    unsigned short* __restrict__ Xout, int M) {
    __shared__ unsigned short lds[16384];  // 32 KB: W0half, W1half; reused as Cs
    __shared__ float bS[128];

    int tid = threadIdx.x;
    int m0 = blockIdx.x * 64;
    int yb = blockIdx.y;

    int wave = tid >> 6, lane = tid & 63;
    int row16 = lane & 15;
    int quad = lane >> 4;
    int wrow = wave * 16;

    // ---- A-fragment + deg prefetch: issue BEFORE weight staging so the ~500-900cyc
    // HBM latency overlaps the 32KB stage + barrier drain.
    int gA = min(m0 + wrow + row16, M - 1);
    short8 ax[4], ag[4];
#pragma unroll
    for (int ks = 0; ks < 4; ++ks) {
        int koff = ks * 32 + quad * 8;
        ax[ks] = *(const short8*)(Xin + (size_t)gA * 128 + koff);
        ag[ks] = *(const short8*)(Agg + (size_t)gA * 128 + koff);
    }
    int dgp[4];
#pragma unroll
    for (int rr = 0; rr < 4; ++rr) {
        int gm = min(m0 + wrow + quad * 4 + rr, M - 1);
        dgp[rr] = degv[gm];
    }

    if (tid < 64) {
        bS[tid] = b0 ? b0[yb * 64 + tid] : 0.f;
        bS[64 + tid] = b1 ? b1[yb * 64 + tid] : 0.f;
    }

    const unsigned short* W0h = Wt + (size_t)yb * 64 * 128;
    const unsigned short* W1h = Wt + 16384 + (size_t)yb * 64 * 128;
#pragma unroll
    for (int l = 0; l < 8; ++l) {
        int idx = tid + l * 256;      // 0..2047
        int half = idx >> 10;
        int r = (idx >> 4) & 63;
        int c16 = idx & 15;
        int sw = (c16 ^ (r & 15)) * 8;
        const unsigned short* src = (half ? W1h : W0h) + r * 128 + c16 * 8;
        *(short8*)&lds[half * 8192 + r * 128 + sw] = *(const short8*)src;
    }
    __syncthreads();

    floatx4 acc[4];
#pragma unroll
    for (int j = 0; j < 4; j++) acc[j] = (floatx4){0.f, 0.f, 0.f, 0.f};

#pragma unroll
    for (int ks = 0; ks < 4; ++ks) {
        int c = ks * 4 + quad;
#pragma unroll
        for (int nt = 0; nt < 4; ++nt) {
            int wr = nt * 16 + row16;
            short8 bw0 = *(short8*)&lds[wr * 128 + ((c ^ row16) * 8)];
            short8 bw1 = *(short8*)&lds[8192 + wr * 128 + ((c ^ row16) * 8)];
            acc[nt] = __builtin_amdgcn_mfma_f32_16x16x32_bf16(ax[ks], bw0, acc[nt], 0, 0, 0);
            acc[nt] = __builtin_amdgcn_mfma_f32_16x16x32_bf16(ag[ks], bw1, acc[nt], 0, 0, 0);
        }
    }
    __syncthreads();  // weights consumed; reuse lds as Cs (64 x pitch-72 bf16 = 9216 B)

    unsigned short* Cs = lds;
#pragma unroll
    for (int nt = 0; nt < 4; ++nt) {
        int colh = nt * 16 + row16;
        int colg = yb * 64 + colh;
        float bc0 = bS[colh];
        float bc1 = bS[64 + colh];
#pragma unroll
        for (int rr = 0; rr < 4; ++rr) {
            int row = wrow + quad * 4 + rr;
            int gm = m0 + row;
            float v = acc[nt][rr] + bc0 + (float)dgp[rr] * bc1;
            if (pre && gm < M) v += pre[(size_t)gm * 128 + colg];
            Cs[row * 72 + colh] = f2bf(fmaxf(v, 0.f));
        }
    }
    __syncthreads();

    int r = tid >> 2;
    int cq = (tid & 3) * 16;
    int gm = m0 + r;
    if (gm < M) {
        unsigned short* dst = Xout + (size_t)gm * 128 + yb * 64 + cq;
        *(short8*)dst = *(short8*)&Cs[r * 72 + cq];
        *(short8*)(dst + 8) = *(short8*)&Cs[r * 72 + cq + 8];
    }
}

// ---------------- head: out = X @ off_w + off_b (wave per vertex) ----------------
__global__ __launch_bounds__(256) void head_k(const unsigned short* __restrict__ X,
                                              const float* __restrict__ off_w,
                                              const float* __restrict__ off_b,
                                              float* __restrict__ out, int Nv) {
    int wave = threadIdx.x >> 6, lane = threadIdx.x & 63;
    int n = blockIdx.x * 4 + wave;
    if (n >= Nv) return;
    unsigned int u = *(const unsigned int*)(X + (size_t)n * 128 + 2 * lane);
    float x0 = bf2f((unsigned short)(u & 0xffff));
    float x1 = bf2f((unsigned short)(u >> 16));
    int c0 = 2 * lane, c1 = 2 * lane + 1;
    float p0 = x0 * off_w[c0 * 3 + 0] + x1 * off_w[c1 * 3 + 0];
    float p1 = x0 * off_w[c0 * 3 + 1] + x1 * off_w[c1 * 3 + 1];
    float p2 = x0 * off_w[c0 * 3 + 2] + x1 * off_w[c1 * 3 + 2];
#pragma unroll
    for (int m = 1; m < 64; m <<= 1) {
        p0 += __shfl_xor(p0, m);
        p1 += __shfl_xor(p1, m);
        p2 += __shfl_xor(p2, m);
    }
    if (lane == 0) {
        out[n * 3 + 0] = p0 + off_b[0];
        out[n * 3 + 1] = p1 + off_b[1];
        out[n * 3 + 2] = p2 + off_b[2];
    }
}

extern "C" void kernel_launch(void* const* d_in, const int* in_sizes, int n_in, void* d_out,
                              int out_size, void* d_ws, size_t ws_size, hipStream_t stream) {
    const float* feat1 = (const float*)d_in[0];
    const float* feat2 = (const float*)d_in[1];
    const float* feat3 = (const float*)d_in[2];
    const float* feat4 = (const float*)d_in[3];
    const float* av = (const float*)d_in[4];
    const float* verts = (const float*)d_in[5];
    const float* image_enc = (const float*)d_in[6];
    const int* edges = (const int*)d_in[7];
    const float* bw = (const float*)d_in[8];
    const float* bb = (const float*)d_in[9];
    const float* g0w0 = (const float*)d_in[10];
    const float* g0b0 = (const float*)d_in[11];
    const float* g0w1 = (const float*)d_in[12];
    const float* g0b1 = (const float*)d_in[13];
    const float* gw0 = (const float*)d_in[14];
    const float* gb0 = (const float*)d_in[15];
    const float* gw1 = (const float*)d_in[16];
    const float* gb1 = (const float*)d_in[17];
    const float* off_w = (const float*)d_in[18];
    const float* off_b = (const float*)d_in[19];

    int B_ = in_sizes[6] / 256;  // 4
    int N_ = in_sizes[5] / 3;    // 40968
    int V_ = N_ / B_;            // 10242
    int E_ = in_sizes[7] / 2;    // 122880

    char* wsb = (char*)d_ws;
    size_t off = 0;
    auto alloc = [&](size_t bytes) -> void* {
        void* p = (void*)(wsb + off);
        off += (bytes + 255) & ~(size_t)255;
        return p;
    };
    int S1 = B_ * 3136 * 128;
    int S2 = B_ * 784 * 128;
    int S3 = B_ * 196 * 128;
    int S4 = B_ * 49 * 128;
    float* pp1 = (float*)alloc((size_t)S1 * 4);
    float* pp2 = (float*)alloc((size_t)S2 * 4);
    float* pp3 = (float*)alloc((size_t)S3 * 4);
    float* pp4 = (float*)alloc((size_t)S4 * 4);
    float* q1 = (float*)alloc((size_t)4 * S1 * 4);
    float* q2 = (float*)alloc((size_t)8 * S2 * 4);
    float* q3 = (float*)alloc((size_t)16 * S3 * 4);
    float* q4 = (float*)alloc((size_t)32 * S4 * 4);
    unsigned short* XA = (unsigned short*)alloc((size_t)N_ * 128 * 2);
    unsigned short* XB = (unsigned short*)alloc((size_t)N_ * 128 * 2);
    unsigned short* AggB = (unsigned short*)alloc((size_t)N_ * 128 * 2);
    unsigned short* Hb = (unsigned short*)alloc((size_t)N_ * 256 * 2);
    float* pre = (float*)alloc((size_t)N_ * 128 * 4);
    unsigned short* Wt = (unsigned short*)alloc((size_t)8 * 2 * 128 * 128 * 2);
    float* encp = (float*)alloc((size_t)2 * B_ * 128 * 4);
    int* deg = (int*)alloc((size_t)(N_ + 1) * 4);
    int* rowptr = (int*)alloc((size_t)(N_ + 1) * 4);
    int* cursor = (int*)alloc((size_t)N_ * 4);
    int* excl = (int*)alloc((size_t)N_ * 4);
    int* bsum = (int*)alloc((size_t)64 * 4);
    int* adj = (int*)alloc((size_t)2 * E_ * 4);

    hipMemsetAsync(deg, 0, (N_ + 1) * sizeof(int), stream);

    // fat prologue: count_deg | prep_w | enc_proj
    int nE = ceil_div(E_, 256);
    fatpre_k<<<nE + 16 + B_, 256, 0, stream>>>(edges, deg, E_, nE, g0w0, g0w1, gw0, gw1, Wt,
                                               image_enc, encp, B_);

    // CSR scan + fill
    int nb = ceil_div(N_, 1024);
    scan1_k<<<nb, 1024, 0, stream>>>(deg, excl, bsum, N_);
    scan2_k<<<1, 64, 0, stream>>>(bsum, nb);
    scan3_k<<<nb, 1024, 0, stream>>>(excl, bsum, deg, rowptr, cursor, N_);
    fill_adj_k<<<ceil_div(E_, 256), 256, 0, stream>>>(edges, cursor, adj, E_);

    // fused pixel projection (all levels, one launch) + 4-level reduce
    int nproj = 49 * B_ * 4 + 13 * B_ * 8 + 4 * B_ * 16 + 1 * B_ * 32;
    proj_all_k<<<nproj, 256, 0, stream>>>(feat1, feat2, feat3, feat4, bw, q1, q2, q3, q4, B_);
    int tot4 = (S1 + S2 + S3 + S4) / 4;
    reduce4_k<<<ceil_div(tot4, 256), 256, 0, stream>>>(q1, q2, q3, q4, pp1, pp2, pp3, pp4, S1,
                                                       S2, S3, S4);

    // sample + bottleneck -> XA (bf16 X0); layer0 pre terms (biases baked) -> Hb (bf16)
    sample_bottleneck_k<<<N_, 128, 0, stream>>>(av, pp1, pp2, pp3, pp4, bb, verts, encp, g0w0,
                                                g0w1, g0b0, g0b1, XA, Hb, V_, B_);

    // layer0 pre = h0pre + sum_nb h1pre
    aggpre_k<<<ceil_div(N_, 4), 256, 0, stream>>>(Hb, rowptr, adj, pre, N_);

    int agrid = ceil_div(N_, 4);
    dim3 ggrid(ceil_div(N_, 64), 2);
    // layer 0: pre supplies all affine terms
    agg_x_k<<<agrid, 256, 0, stream>>>(XA, rowptr, adj, AggB, N_);
    gemm_dual_k<<<ggrid, 256, 0, stream>>>(XA, AggB, Wt, nullptr, nullptr, pre, deg, XB, N_);
    unsigned short* Xc = XB;
    unsigned short* Xn = XA;
    for (int i = 0; i < 7; ++i) {
        agg_x_k<<<agrid, 256, 0, stream>>>(Xc, rowptr, adj, AggB, N_);
        gemm_dual_k<<<ggrid, 256, 0, stream>>>(Xc, AggB, Wt + (size_t)(i + 1) * 32768,
                                               gb0 + i * 128, gb1 + i * 128, nullptr, deg, Xn,
                                               N_);
        unsigned short* t = Xc;
        Xc = Xn;
        Xn = t;
    }
    head_k<<<ceil_div(N_, 4), 256, 0, stream>>>(Xc, off_w, off_b, (float*)d_out, N_);
}

// Round 12
// 491.404 us; speedup vs baseline: 8.7914x; 1.2084x over previous
//
#include <hip/hip_runtime.h>

static inline int ceil_div(int a, int b) { return (a + b - 1) / b; }

typedef __attribute__((ext_vector_type(8))) short short8;
typedef __attribute__((ext_vector_type(4))) float floatx4;

__device__ __forceinline__ unsigned short f2bf(float f) {
    unsigned int u = __float_as_uint(f);
    unsigned int r = (u + 0x7fffu + ((u >> 16) & 1u)) >> 16;
    return (unsigned short)r;
}
__device__ __forceinline__ float bf2f(unsigned short h) {
    return __uint_as_float(((unsigned int)h) << 16);
}

// ---------------- CSR scan ----------------
__global__ __launch_bounds__(1024) void scan1_k(const int* __restrict__ deg,
                                                int* __restrict__ excl,
                                                int* __restrict__ bsum, int Nv) {
    __shared__ int s[1024];
    int tid = threadIdx.x;
    int i = blockIdx.x * 1024 + tid;
    int v = (i < Nv) ? deg[i] : 0;
    s[tid] = v;
    __syncthreads();
    for (int off = 1; off < 1024; off <<= 1) {
        int t = (tid >= off) ? s[tid - off] : 0;
        __syncthreads();
        if (tid >= off) s[tid] += t;
        __syncthreads();
    }
    if (i < Nv) excl[i] = s[tid] - v;
    if (tid == 1023) bsum[blockIdx.x] = s[1023];
}

__global__ __launch_bounds__(64) void scan2_k(int* __restrict__ bsum, int nb) {
    __shared__ int s[64];
    int tid = threadIdx.x;
    int v = (tid < nb) ? bsum[tid] : 0;
    s[tid] = v;
    __syncthreads();
    for (int off = 1; off < 64; off <<= 1) {
        int t = (tid >= off) ? s[tid - off] : 0;
        __syncthreads();
        if (tid >= off) s[tid] += t;
        __syncthreads();
    }
    if (tid < nb) bsum[tid] = s[tid] - v;
}

__global__ __launch_bounds__(1024) void scan3_k(const int* __restrict__ excl,
                                                const int* __restrict__ bsum,
                                                const int* __restrict__ deg,
                                                int* __restrict__ rowptr,
                                                int* __restrict__ cursor, int Nv) {
    int i = blockIdx.x * 1024 + threadIdx.x;
    if (i < Nv) {
        int val = excl[i] + bsum[blockIdx.x];
        rowptr[i] = val;
        cursor[i] = val;
        if (i == Nv - 1) rowptr[Nv] = val + deg[i];
    }
}

__global__ __launch_bounds__(256) void fill_adj_k(const int* __restrict__ edges,
                                                  int* __restrict__ cursor,
                                                  int* __restrict__ adj, int E) {
    int e = blockIdx.x * blockDim.x + threadIdx.x;
    if (e < E) {
        int a = edges[2 * e], b = edges[2 * e + 1];
        adj[atomicAdd(&cursor[a], 1)] = b;
        adj[atomicAdd(&cursor[b], 1)] = a;
    }
}

// ---------------- fat prologue: count_deg | prep_w | enc_proj ----------------
__global__ __launch_bounds__(256) void fatpre_k(const int* __restrict__ edges,
                                                int* __restrict__ deg, int E, int nE,
                                                const float* __restrict__ g0w0,
                                                const float* __restrict__ g0w1,
                                                const float* __restrict__ gw0,
                                                const float* __restrict__ gw1,
                                                unsigned short* __restrict__ Wt,
                                                const float* __restrict__ enc,
                                                float* __restrict__ encp, int B_) {
    int bid = blockIdx.x;
    int tid = threadIdx.x;
    if (bid < nE) {
        int e = bid * 256 + tid;
        if (e < E) {
            atomicAdd(&deg[edges[2 * e]], 1);
            atomicAdd(&deg[edges[2 * e + 1]], 1);
        }
    } else if (bid < nE + 16) {
        int lh = bid - nE;
        int l = lh >> 1, h = lh & 1;
        const float* src;
        if (l == 0) src = h ? g0w1 : g0w0;
        else src = (h ? gw1 : gw0) + (size_t)(l - 1) * 16384;
        unsigned short* dst = Wt + (size_t)lh * 16384;
        for (int idx = tid; idx < 16384; idx += 256) {
            int n = idx >> 7, k = idx & 127;
            dst[n * 128 + k] = f2bf(src[k * 128 + n]);
        }
    } else {
        int b = bid - nE - 16;
        int sH = tid >> 7;
        int j = tid & 127;
        const float* w = sH ? g0w1 : g0w0;
        const float* eb = enc + b * 256;
        float acc = 0.f;
        for (int c = 0; c < 256; ++c) acc = fmaf(eb[c], w[(131 + c) * 128 + j], acc);
        encp[(sH * B_ + b) * 128 + j] = acc;
    }
}

// ---------------- fused pixel projection (all 4 levels, one launch) ----------------
__global__ __launch_bounds__(256) void proj_all_k(
    const float* __restrict__ fm1, const float* __restrict__ fm2,
    const float* __restrict__ fm3, const float* __restrict__ fm4,
    const float* __restrict__ bw, float* __restrict__ q1, float* __restrict__ q2,
    float* __restrict__ q3, float* __restrict__ q4, int B_) {
    __shared__ float Xs[32][64];
    __shared__ float Ws[32][128];
    int tid = threadIdx.x;

    int n1 = 49 * B_ * 4, n2 = 13 * B_ * 8, n3 = 4 * B_ * 16;
    int bid = blockIdx.x;
    const float* fm;
    const float* W;
    float* op;
    int C, HW, PT, idx;
    if (bid < n1) {
        fm = fm1; W = bw; op = q1; C = 256; HW = 3136; PT = 49; idx = bid;
    } else if (bid < n1 + n2) {
        fm = fm2; W = bw + 256 * 128; op = q2; C = 512; HW = 784; PT = 13; idx = bid - n1;
    } else if (bid < n1 + n2 + n3) {
        fm = fm3; W = bw + 768 * 128; op = q3; C = 1024; HW = 196; PT = 4; idx = bid - n1 - n2;
    } else {
        fm = fm4; W = bw + 1792 * 128; op = q4; C = 2048; HW = 49; PT = 1;
        idx = bid - n1 - n2 - n3;
    }
    int pt = idx % PT;
    int r2 = idx / PT;
    int b = r2 % B_;
    int zz = r2 / B_;
    int p0 = pt * 64;
    int c0 = zz * 64;
    int S = B_ * HW * 128;
    const float* fmb = fm + (size_t)b * C * HW;

    float acc[8][4];
#pragma unroll
    for (int i = 0; i < 8; i++)
#pragma unroll
        for (int j = 0; j < 4; j++) acc[i][j] = 0.f;

    bool vec_ok = ((HW & 3) == 0);
    for (int kc = c0; kc < c0 + 64; kc += 32) {
        {
            int p4 = (tid & 15) * 4;
            int k0 = tid >> 4;
#pragma unroll
            for (int kk = 0; kk < 32; kk += 16) {
                int k = k0 + kk;
                const float* src = fmb + (size_t)(kc + k) * HW + p0 + p4;
                float4 v;
                if (vec_ok && (p0 + p4 + 3 < HW)) {
                    v = *(const float4*)src;
                } else {
                    v.x = (p0 + p4 + 0 < HW) ? src[0] : 0.f;
                    v.y = (p0 + p4 + 1 < HW) ? src[1] : 0.f;
                    v.z = (p0 + p4 + 2 < HW) ? src[2] : 0.f;
                    v.w = (p0 + p4 + 3 < HW) ? src[3] : 0.f;
                }
                *(float4*)&Xs[k][p4] = v;
            }
        }
        {
            int j4 = (tid & 31) * 4;
            int k0 = tid >> 5;
#pragma unroll
            for (int kk = 0; kk < 32; kk += 8) {
                int k = k0 + kk;
                *(float4*)&Ws[k][j4] = *(const float4*)(W + (size_t)(kc + k) * 128 + j4);
            }
        }
        __syncthreads();
        int rb = (tid >> 5) * 8;
        int cb = (tid & 31) * 4;
#pragma unroll 8
        for (int k = 0; k < 32; ++k) {
            float xr[8], wc[4];
#pragma unroll
            for (int i = 0; i < 8; i++) xr[i] = Xs[k][rb + i];
#pragma unroll
            for (int j = 0; j < 4; j++) wc[j] = Ws[k][cb + j];
#pragma unroll
            for (int i = 0; i < 8; i++)
#pragma unroll
                for (int j = 0; j < 4; j++) acc[i][j] = fmaf(xr[i], wc[j], acc[i][j]);
        }
        __syncthreads();
    }
    int rb = (tid >> 5) * 8;
    int cb = (tid & 31) * 4;
    float* obase = op + (size_t)zz * S;
#pragma unroll
    for (int i = 0; i < 8; i++) {
        int p = p0 + rb + i;
        if (p < HW) {
            *(float4*)(obase + ((size_t)b * HW + p) * 128 + cb) =
                make_float4(acc[i][0], acc[i][1], acc[i][2], acc[i][3]);
        }
    }
}

// ---------------- reduce partials for all 4 levels ----------------
__global__ __launch_bounds__(256) void reduce4_k(const float* __restrict__ q1,
                                                 const float* __restrict__ q2,
                                                 const float* __restrict__ q3,
                                                 const float* __restrict__ q4,
                                                 float* __restrict__ o1, float* __restrict__ o2,
                                                 float* __restrict__ o3, float* __restrict__ o4,
                                                 int S1, int S2, int S3, int S4) {
    int i = (blockIdx.x * 256 + threadIdx.x) * 4;
    const float* src;
    float* dst;
    int S, z, base;
    if (i < S1) {
        src = q1; dst = o1; S = S1; z = 4; base = i;
    } else if (i < S1 + S2) {
        src = q2; dst = o2; S = S2; z = 8; base = i - S1;
    } else if (i < S1 + S2 + S3) {
        src = q3; dst = o3; S = S3; z = 16; base = i - S1 - S2;
    } else if (i < S1 + S2 + S3 + S4) {
        src = q4; dst = o4; S = S4; z = 32; base = i - S1 - S2 - S3;
    } else {
        return;
    }
    float4 a = *(const float4*)(src + base);
    for (int zz = 1; zz < z; ++zz) {
        float4 b = *(const float4*)(src + (size_t)zz * S + base);
        a.x += b.x; a.y += b.y; a.z += b.z; a.w += b.w;
    }
    *(float4*)(dst + base) = a;
}

// ---------------- bilinear sample + bottleneck relu + layer0 pre terms ----------------
__device__ __forceinline__ float sample_level(const float* __restrict__ pp, int Hh, int Ww,
                                              float gx, float gy, int j) {
    float x = (gx + 1.f) * 0.5f * (float)(Ww - 1);
    float y = (gy + 1.f) * 0.5f * (float)(Hh - 1);
    float x0f = floorf(x), y0f = floorf(y);
    float wx1 = x - x0f, wy1 = y - y0f;
    float wx0 = 1.f - wx1, wy0 = 1.f - wy1;
    int x0 = (int)fminf(fmaxf(x0f, 0.f), (float)(Ww - 1));
    int x1 = (int)fminf(fmaxf(x0f + 1.f, 0.f), (float)(Ww - 1));
    int y0 = (int)fminf(fmaxf(y0f, 0.f), (float)(Hh - 1));
    int y1 = (int)fminf(fmaxf(y0f + 1.f, 0.f), (float)(Hh - 1));
    const float* r00 = pp + (size_t)(y0 * Ww + x0) * 128;
    const float* r01 = pp + (size_t)(y0 * Ww + x1) * 128;
    const float* r10 = pp + (size_t)(y1 * Ww + x0) * 128;
    const float* r11 = pp + (size_t)(y1 * Ww + x1) * 128;
    return wy0 * (wx0 * r00[j] + wx1 * r01[j]) + wy1 * (wx0 * r10[j] + wx1 * r11[j]);
}

__global__ __launch_bounds__(128) void sample_bottleneck_k(
    const float* __restrict__ av, const float* __restrict__ pp1, const float* __restrict__ pp2,
    const float* __restrict__ pp3, const float* __restrict__ pp4, const float* __restrict__ bb,
    const float* __restrict__ verts, const float* __restrict__ encp,
    const float* __restrict__ g0w0, const float* __restrict__ g0w1,
    const float* __restrict__ g0b0, const float* __restrict__ g0b1,
    unsigned short* __restrict__ X, unsigned short* __restrict__ H, int V_, int B_) {
    int n = blockIdx.x, j = threadIdx.x;
    int b = n / V_;
    float gx = av[(size_t)n * 3 + 0];
    float gy = av[(size_t)n * 3 + 1];
    float acc = bb[j];
    acc += sample_level(pp1 + (size_t)b * 3136 * 128, 56, 56, gx, gy, j);
    acc += sample_level(pp2 + (size_t)b * 784 * 128, 28, 28, gx, gy, j);
    acc += sample_level(pp3 + (size_t)b * 196 * 128, 14, 14, gx, gy, j);
    acc += sample_level(pp4 + (size_t)b * 49 * 128, 7, 7, gx, gy, j);
    X[(size_t)n * 128 + j] = f2bf(fmaxf(acc, 0.f));
    float v0 = verts[n * 3 + 0], v1 = verts[n * 3 + 1], v2 = verts[n * 3 + 2];
    float h0 = encp[(0 * B_ + b) * 128 + j] + g0b0[j] + v0 * g0w0[128 * 128 + j] +
               v1 * g0w0[129 * 128 + j] + v2 * g0w0[130 * 128 + j];
    float h1 = encp[(1 * B_ + b) * 128 + j] + g0b1[j] + v0 * g0w1[128 * 128 + j] +
               v1 * g0w1[129 * 128 + j] + v2 * g0w1[130 * 128 + j];
    H[(size_t)n * 256 + j] = f2bf(h0);
    H[(size_t)n * 256 + 128 + j] = f2bf(h1);
}

// ---------------- layer-0 pre: pre[n] = h0pre[n] + sum_nb h1pre[nb] (fp32) ----------------
// 8-wide batched neighbor prefetch for gather ILP.
__global__ __launch_bounds__(256) void aggpre_k(const unsigned short* __restrict__ H,
                                                const int* __restrict__ rowptr,
                                                const int* __restrict__ adj,
                                                float* __restrict__ pre, int Nv) {
    int wave = threadIdx.x >> 6, lane = threadIdx.x & 63;
    int n = blockIdx.x * 4 + wave;
    if (n >= Nv) return;
    unsigned int u = *(const unsigned int*)(H + (size_t)n * 256 + 2 * lane);
    float a0 = bf2f((unsigned short)(u & 0xffff));
    float a1 = bf2f((unsigned short)(u >> 16));
    int s = rowptr[n], e = rowptr[n + 1];
    for (int t = s; t < e; t += 8) {
        int nb[8];
        unsigned int w[8];
#pragma unroll
        for (int q = 0; q < 8; ++q) {
            int idx = (t + q < e) ? (t + q) : (e - 1);
            nb[q] = adj[idx];
        }
#pragma unroll
        for (int q = 0; q < 8; ++q)
            w[q] = *(const unsigned int*)(H + (size_t)nb[q] * 256 + 128 + 2 * lane);
#pragma unroll
        for (int q = 0; q < 8; ++q) {
            if (t + q < e) {
                a0 += bf2f((unsigned short)(w[q] & 0xffff));
                a1 += bf2f((unsigned short)(w[q] >> 16));
            }
        }
    }
    pre[(size_t)n * 128 + 2 * lane] = a0;
    pre[(size_t)n * 128 + 2 * lane + 1] = a1;
}

// ---------------- neighbor aggregation with 8-wide batched prefetch ----------------
__global__ __launch_bounds__(256) void agg_x_k(const unsigned short* __restrict__ X,
                                               const int* __restrict__ rowptr,
                                               const int* __restrict__ adj,
                                               unsigned short* __restrict__ Agg, int Nv) {
    int wave = threadIdx.x >> 6, lane = threadIdx.x & 63;
    int n = blockIdx.x * 4 + wave;
    if (n >= Nv) return;
    const unsigned int* Xu = (const unsigned int*)X;
    float a0 = 0.f, a1 = 0.f;
    int s = rowptr[n], e = rowptr[n + 1];
    for (int t = s; t < e; t += 8) {
        int nb[8];
        unsigned int w[8];
#pragma unroll
        for (int q = 0; q < 8; ++q) {
            int idx = (t + q < e) ? (t + q) : (e - 1);
            nb[q] = adj[idx];
        }
#pragma unroll
        for (int q = 0; q < 8; ++q) w[q] = Xu[(size_t)nb[q] * 64 + lane];
#pragma unroll
        for (int q = 0; q < 8; ++q) {
            if (t + q < e) {
                a0 += bf2f((unsigned short)(w[q] & 0xffff));
                a1 += bf2f((unsigned short)(w[q] >> 16));
            }
        }
    }
    unsigned int o = (unsigned int)f2bf(a0) | ((unsigned int)f2bf(a1) << 16);
    *(unsigned int*)(Agg + (size_t)n * 128 + 2 * lane) = o;
}

// ---------------- dual-MFMA layer GEMM v3: 128-row x 64-col tiles ----------------
// grid = (ceil(M/128), 2). Weights (32 KB for the 64-col half pair) staged ONCE,
// two 64-row sub-tiles computed sequentially -> weight traffic halved vs 64x64.
// Sub-tile A-fragments prefetched ahead (tile1's loads overlap tile0's MFMA).
__global__ __launch_bounds__(256, 3) void gemm_dual_k(
    const unsigned short* __restrict__ Xin, const unsigned short* __restrict__ Agg,
    const unsigned short* __restrict__ Wt,  // [2][128][128] bf16 n-major (W0, W1)
    const float* __restrict__ b0, const float* __restrict__ b1,
    const float* __restrict__ pre, const int* __restrict__ degv,
    unsigned short* __restrict__ Xout, int M) {
    __shared__ unsigned short wlds[16384];  // 32 KB weights (stays live both sub-tiles)
    __shared__ unsigned short cs[64 * 72];  // 9 KB epilogue staging
    __shared__ float bS[128];

    int tid = threadIdx.x;
    int m0 = blockIdx.x * 128;
    int yb = blockIdx.y;

    int wave = tid >> 6, lane = tid & 63;
    int row16 = lane & 15;
    int quad = lane >> 4;
    int wrow = wave * 16;

    // prefetch A + deg for sub-tile 0 (overlaps weight staging)
    short8 axT[2][4], agT[2][4];
    int dgT[2][4];
    {
        int g = min(m0 + wrow + row16, M - 1);
#pragma unroll
        for (int ks = 0; ks < 4; ++ks) {
            int koff = ks * 32 + quad * 8;
            axT[0][ks] = *(const short8*)(Xin + (size_t)g * 128 + koff);
            agT[0][ks] = *(const short8*)(Agg + (size_t)g * 128 + koff);
        }
#pragma unroll
        for (int rr = 0; rr < 4; ++rr)
            dgT[0][rr] = degv[min(m0 + wrow + quad * 4 + rr, M - 1)];
    }

    if (tid < 64) {
        bS[tid] = b0 ? b0[yb * 64 + tid] : 0.f;
        bS[64 + tid] = b1 ? b1[yb * 64 + tid] : 0.f;
    }

    const unsigned short* W0h = Wt + (size_t)yb * 64 * 128;
    const unsigned short* W1h = Wt + 16384 + (size_t)yb * 64 * 128;
#pragma unroll
    for (int l = 0; l < 8; ++l) {
        int idx = tid + l * 256;      // 0..2047 16B chunks
        int half = idx >> 10;
        int r = (idx >> 4) & 63;
        int c16 = idx & 15;
        int sw = (c16 ^ (r & 15)) * 8;
        const unsigned short* src = (half ? W1h : W0h) + r * 128 + c16 * 8;
        *(short8*)&wlds[half * 8192 + r * 128 + sw] = *(const short8*)src;
    }
    __syncthreads();

    // prefetch A + deg for sub-tile 1 (overlaps sub-tile-0 MFMA)
    {
        int g = min(m0 + 64 + wrow + row16, M - 1);
#pragma unroll
        for (int ks = 0; ks < 4; ++ks) {
            int koff = ks * 32 + quad * 8;
            axT[1][ks] = *(const short8*)(Xin + (size_t)g * 128 + koff);
            agT[1][ks] = *(const short8*)(Agg + (size_t)g * 128 + koff);
        }
#pragma unroll
        for (int rr = 0; rr < 4; ++rr)
            dgT[1][rr] = degv[min(m0 + 64 + wrow + quad * 4 + rr, M - 1)];
    }

#pragma unroll
    for (int t = 0; t < 2; ++t) {
        int mT = m0 + t * 64;
        floatx4 acc[4];
#pragma unroll
        for (int j = 0; j < 4; j++) acc[j] = (floatx4){0.f, 0.f, 0.f, 0.f};

#pragma unroll
        for (int ks = 0; ks < 4; ++ks) {
            int c = ks * 4 + quad;
#pragma unroll
            for (int nt = 0; nt < 4; ++nt) {
                int wr = nt * 16 + row16;
                short8 bw0 = *(short8*)&wlds[wr * 128 + ((c ^ row16) * 8)];
                short8 bw1 = *(short8*)&wlds[8192 + wr * 128 + ((c ^ row16) * 8)];
                acc[nt] = __builtin_amdgcn_mfma_f32_16x16x32_bf16(axT[t][ks], bw0, acc[nt], 0, 0, 0);
                acc[nt] = __builtin_amdgcn_mfma_f32_16x16x32_bf16(agT[t][ks], bw1, acc[nt], 0, 0, 0);
            }
        }

        // epilogue -> cs (each wave writes its own 16 rows)
#pragma unroll
        for (int nt = 0; nt < 4; ++nt) {
            int colh = nt * 16 + row16;
            int colg = yb * 64 + colh;
            float bc0 = bS[colh];
            float bc1 = bS[64 + colh];
#pragma unroll
            for (int rr = 0; rr < 4; ++rr) {
                int row = wrow + quad * 4 + rr;
                int gm = mT + row;
                float v = acc[nt][rr] + bc0 + (float)dgT[t][rr] * bc1;
                if (pre && gm < M) v += pre[(size_t)gm * 128 + colg];
                cs[row * 72 + colh] = f2bf(fmaxf(v, 0.f));
            }
        }
        __syncthreads();

        // coalesced copy-out
        {
            int r = tid >> 2;
            int cq = (tid & 3) * 16;
            int gm = mT + r;
            if (gm < M) {
                unsigned short* dst = Xout + (size_t)gm * 128 + yb * 64 + cq;
                *(short8*)dst = *(short8*)&cs[r * 72 + cq];
                *(short8*)(dst + 8) = *(short8*)&cs[r * 72 + cq + 8];
            }
        }
        __syncthreads();  // cs reads done before next sub-tile overwrites
    }
}

// ---------------- head: out = X @ off_w + off_b (wave per vertex) ----------------
__global__ __launch_bounds__(256) void head_k(const unsigned short* __restrict__ X,
                                              const float* __restrict__ off_w,
                                              const float* __restrict__ off_b,
                                              float* __restrict__ out, int Nv) {
    int wave = threadIdx.x >> 6, lane = threadIdx.x & 63;
    int n = blockIdx.x * 4 + wave;
    if (n >= Nv) return;
    unsigned int u = *(const unsigned int*)(X + (size_t)n * 128 + 2 * lane);
    float x0 = bf2f((unsigned short)(u & 0xffff));
    float x1 = bf2f((unsigned short)(u >> 16));
    int c0 = 2 * lane, c1 = 2 * lane + 1;
    float p0 = x0 * off_w[c0 * 3 + 0] + x1 * off_w[c1 * 3 + 0];
    float p1 = x0 * off_w[c0 * 3 + 1] + x1 * off_w[c1 * 3 + 1];
    float p2 = x0 * off_w[c0 * 3 + 2] + x1 * off_w[c1 * 3 + 2];
#pragma unroll
    for (int m = 1; m < 64; m <<= 1) {
        p0 += __shfl_xor(p0, m);
        p1 += __shfl_xor(p1, m);
        p2 += __shfl_xor(p2, m);
    }
    if (lane == 0) {
        out[n * 3 + 0] = p0 + off_b[0];
        out[n * 3 + 1] = p1 + off_b[1];
        out[n * 3 + 2] = p2 + off_b[2];
    }
}

extern "C" void kernel_launch(void* const* d_in, const int* in_sizes, int n_in, void* d_out,
                              int out_size, void* d_ws, size_t ws_size, hipStream_t stream) {
    const float* feat1 = (const float*)d_in[0];
    const float* feat2 = (const float*)d_in[1];
    const float* feat3 = (const float*)d_in[2];
    const float* feat4 = (const float*)d_in[3];
    const float* av = (const float*)d_in[4];
    const float* verts = (const float*)d_in[5];
    const float* image_enc = (const float*)d_in[6];
    const int* edges = (const int*)d_in[7];
    const float* bw = (const float*)d_in[8];
    const float* bb = (const float*)d_in[9];
    const float* g0w0 = (const float*)d_in[10];
    const float* g0b0 = (const float*)d_in[11];
    const float* g0w1 = (const float*)d_in[12];
    const float* g0b1 = (const float*)d_in[13];
    const float* gw0 = (const float*)d_in[14];
    const float* gb0 = (const float*)d_in[15];
    const float* gw1 = (const float*)d_in[16];
    const float* gb1 = (const float*)d_in[17];
    const float* off_w = (const float*)d_in[18];
    const float* off_b = (const float*)d_in[19];

    int B_ = in_sizes[6] / 256;  // 4
    int N_ = in_sizes[5] / 3;    // 40968
    int V_ = N_ / B_;            // 10242
    int E_ = in_sizes[7] / 2;    // 122880

    char* wsb = (char*)d_ws;
    size_t off = 0;
    auto alloc = [&](size_t bytes) -> void* {
        void* p = (void*)(wsb + off);
        off += (bytes + 255) & ~(size_t)255;
        return p;
    };
    int S1 = B_ * 3136 * 128;
    int S2 = B_ * 784 * 128;
    int S3 = B_ * 196 * 128;
    int S4 = B_ * 49 * 128;
    float* pp1 = (float*)alloc((size_t)S1 * 4);
    float* pp2 = (float*)alloc((size_t)S2 * 4);
    float* pp3 = (float*)alloc((size_t)S3 * 4);
    float* pp4 = (float*)alloc((size_t)S4 * 4);
    float* q1 = (float*)alloc((size_t)4 * S1 * 4);
    float* q2 = (float*)alloc((size_t)8 * S2 * 4);
    float* q3 = (float*)alloc((size_t)16 * S3 * 4);
    float* q4 = (float*)alloc((size_t)32 * S4 * 4);
    unsigned short* XA = (unsigned short*)alloc((size_t)N_ * 128 * 2);
    unsigned short* XB = (unsigned short*)alloc((size_t)N_ * 128 * 2);
    unsigned short* AggB = (unsigned short*)alloc((size_t)N_ * 128 * 2);
    unsigned short* Hb = (unsigned short*)alloc((size_t)N_ * 256 * 2);
    float* pre = (float*)alloc((size_t)N_ * 128 * 4);
    unsigned short* Wt = (unsigned short*)alloc((size_t)8 * 2 * 128 * 128 * 2);
    float* encp = (float*)alloc((size_t)2 * B_ * 128 * 4);
    int* deg = (int*)alloc((size_t)(N_ + 1) * 4);
    int* rowptr = (int*)alloc((size_t)(N_ + 1) * 4);
    int* cursor = (int*)alloc((size_t)N_ * 4);
    int* excl = (int*)alloc((size_t)N_ * 4);
    int* bsum = (int*)alloc((size_t)64 * 4);
    int* adj = (int*)alloc((size_t)2 * E_ * 4);

    hipMemsetAsync(deg, 0, (N_ + 1) * sizeof(int), stream);

    // fat prologue: count_deg | prep_w | enc_proj
    int nE = ceil_div(E_, 256);
    fatpre_k<<<nE + 16 + B_, 256, 0, stream>>>(edges, deg, E_, nE, g0w0, g0w1, gw0, gw1, Wt,
                                               image_enc, encp, B_);

    // CSR scan + fill
    int nb = ceil_div(N_, 1024);
    scan1_k<<<nb, 1024, 0, stream>>>(deg, excl, bsum, N_);
    scan2_k<<<1, 64, 0, stream>>>(bsum, nb);
    scan3_k<<<nb, 1024, 0, stream>>>(excl, bsum, deg, rowptr, cursor, N_);
    fill_adj_k<<<ceil_div(E_, 256), 256, 0, stream>>>(edges, cursor, adj, E_);

    // fused pixel projection (all levels, one launch) + 4-level reduce
    int nproj = 49 * B_ * 4 + 13 * B_ * 8 + 4 * B_ * 16 + 1 * B_ * 32;
    proj_all_k<<<nproj, 256, 0, stream>>>(feat1, feat2, feat3, feat4, bw, q1, q2, q3, q4, B_);
    int tot4 = (S1 + S2 + S3 + S4) / 4;
    reduce4_k<<<ceil_div(tot4, 256), 256, 0, stream>>>(q1, q2, q3, q4, pp1, pp2, pp3, pp4, S1,
                                                       S2, S3, S4);

    // sample + bottleneck -> XA (bf16 X0); layer0 pre terms (biases baked) -> Hb (bf16)
    sample_bottleneck_k<<<N_, 128, 0, stream>>>(av, pp1, pp2, pp3, pp4, bb, verts, encp, g0w0,
                                                g0w1, g0b0, g0b1, XA, Hb, V_, B_);

    // layer0 pre = h0pre + sum_nb h1pre
    aggpre_k<<<ceil_div(N_, 4), 256, 0, stream>>>(Hb, rowptr, adj, pre, N_);

    int agrid = ceil_div(N_, 4);
    dim3 ggrid(ceil_div(N_, 128), 2);
    // layer 0: pre supplies all affine terms
    agg_x_k<<<agrid, 256, 0, stream>>>(XA, rowptr, adj, AggB, N_);
    gemm_dual_k<<<ggrid, 256, 0, stream>>>(XA, AggB, Wt, nullptr, nullptr, pre, deg, XB, N_);
    unsigned short* Xc = XB;
    unsigned short* Xn = XA;
    for (int i = 0; i < 7; ++i) {
        agg_x_k<<<agrid, 256, 0, stream>>>(Xc, rowptr, adj, AggB, N_);
        gemm_dual_k<<<ggrid, 256, 0, stream>>>(Xc, AggB, Wt + (size_t)(i + 1) * 32768,
                                               gb0 + i * 128, gb1 + i * 128, nullptr, deg, Xn,
                                               N_);
        unsigned short* t = Xc;
        Xc = Xn;
        Xn = t;
    }
    head_k<<<ceil_div(N_, 4), 256, 0, stream>>>(Xc, off_w, off_b, (float*)d_out, N_);
}